// Round 11
// baseline (38.139 us; speedup 1.0000x reference)
//
#include <hip/hip_runtime.h>

#define NOUT 83
#define NHEART 27
#define NLUNG 28

typedef float v4f __attribute__((ext_vector_type(4)));

// forced 16B global load (volatile asm -> compiler can't split/shrink pipeline)
#define GLOAD(dst, ptr, offs) \
    asm volatile("global_load_dwordx4 %0, %1, off offset:" offs \
                 : "=v"(dst) : "v"(ptr))

#define WAITV(lit) \
    asm volatile("s_waitcnt vmcnt(" lit ")" ::: "memory"); \
    __builtin_amdgcn_sched_barrier(0)

// position class of step u (period 9): (64*u) mod 144
constexpr int kPOS[9] = {0, 64, 128, 48, 112, 32, 96, 16, 80};

// consume step u from t[(u)&7] into wave-private region (LDS RMW)
#define DRAIN(u, lit) { \
    int p = kPOS[(u) % 9] + l; if (p >= 144) p -= 144; \
    v4f cur = region[p]; \
    asm volatile("s_waitcnt vmcnt(" lit ")" ::: "memory"); \
    __builtin_amdgcn_sched_barrier(0); \
    region[p] = cur + t[(u) & 7]; }

// Stream NFULL sequential 1KB steps (64 lanes x 16B) of one half-volume,
// 8-deep rolling pipeline: preload 8, {consume oldest + reissue} x (NFULL-8),
// drain 8 with counted vmcnt. Each consumed step is RMW'd into the wave's
// private 144-quad LDS region at position (64*step + l) mod 144.
template<int NFULL>
__device__ __forceinline__ void stream_half(const v4f* srcq, v4f* region, int l)
{
    v4f t[8];
    const v4f* pA = srcq;
    const v4f* pB = srcq + 256;           // +4096 B
    GLOAD(t[0], pA, "0");    GLOAD(t[1], pA, "1024");
    GLOAD(t[2], pA, "2048"); GLOAD(t[3], pA, "3072");
    GLOAD(t[4], pB, "0");    GLOAD(t[5], pB, "1024");
    GLOAD(t[6], pB, "2048"); GLOAD(t[7], pB, "3072");
    const v4f* P = srcq + 512;            // reissue addr: step 8

    #pragma unroll
    for (int u = 0; u <= NFULL - 9; ++u) {
        int p = kPOS[u % 9] + l; if (p >= 144) p -= 144;
        v4f cur = region[p];              // ds_read overlaps the vmcnt wait
        WAITV("7");                       // oldest (step u) returned
        region[p] = cur + t[u & 7];
        GLOAD(t[u & 7], P, "0");          // reissue step u+8
        P += 64;                          // +1024 B
    }
    constexpr int D0 = NFULL - 8;
    DRAIN(D0 + 0, "7"); DRAIN(D0 + 1, "6"); DRAIN(D0 + 2, "5"); DRAIN(D0 + 3, "4");
    DRAIN(D0 + 4, "3"); DRAIN(D0 + 5, "2"); DRAIN(D0 + 6, "1"); DRAIN(D0 + 7, "0");
}

// Block: 1024 threads = 16 waves = 8 volumes x 2 half-waves.
// Half h=0: steps 0..17 (18 full). h=1: steps 18..32 (15 full) + partial 33.
// Split at 18 (multiple of 9) keeps position classes identical in both halves.
// Grid 512 -> 2 blocks/CU = 32 waves/CU (needs VGPR <= 64; streaming uses
// t[8]=32 + pointers, no acc registers - consume goes straight to LDS).
// FC: 64 groups x 16 lanes; group g -> rows o = g + 64k (k<2) x 8 volumes.
__global__ __launch_bounds__(1024) void bodyavg_hilo(
    const v4f* __restrict__ x4,      // [B*2160] quads
    const float* __restrict__ dzh,   // [27,16]
    const float* __restrict__ dzl,   // [28,16]
    const v4f* __restrict__ fcw4,    // [83,144] quads
    const float* __restrict__ fcb,   // [83]
    float* __restrict__ out,         // [B,83]
    int B)
{
    __shared__ float attn_lds[NOUT * 17];
    __shared__ v4f   xms[16][144];       // per-(volume,half) slice-SUM

    const int tid = threadIdx.x;
    const int blk = blockIdx.x;
    const int b0  = blk * 8;

    const int w = tid >> 6;       // wave 0..15
    const int l = tid & 63;
    const int v = w >> 1;         // volume slot 0..7
    const int h = w & 1;          // half 0/1
    const int b = b0 + v;

    v4f* region = xms[w];
    {   // zero own wave's region (wave-private, no barrier needed)
        const v4f z = {0.f, 0.f, 0.f, 0.f};
        region[l] = z; region[64 + l] = z;
        if (l < 16) region[128 + l] = z;
    }

    if (b < B) {
        const v4f* srcq = x4 + (size_t)b * 2160 + h * 1152 + l;
        if (h == 0) {
            stream_half<18>(srcq, region, l);
        } else {
            stream_half<15>(srcq, region, l);
            if (l < 48) {                 // step 33 (global), j=6, no wrap
                const v4f tt = srcq[960];
                region[96 + l] += tt;
            }
        }
    }

    // ---- softmax over 16 channels per disease row (1/15 folded in) ----
    if (tid < NOUT) {
        const int o = tid;
        const float* row = (o < NHEART) ? (dzh + o * 16)
                                        : (dzl + ((o - NHEART) % NLUNG) * 16);
        float vals[16];
        #pragma unroll
        for (int c = 0; c < 16; ++c) vals[c] = row[c];
        float m = vals[0];
        #pragma unroll
        for (int c = 1; c < 16; ++c) m = fmaxf(m, vals[c]);
        float s = 0.f;
        #pragma unroll
        for (int c = 0; c < 16; ++c) { vals[c] = expf(vals[c] - m); s += vals[c]; }
        const float inv = (1.0f / s) * (1.0f / 15.0f);
        #pragma unroll
        for (int c = 0; c < 16; ++c) attn_lds[o * 17 + c] = vals[c] * inv;
    }

    __syncthreads();

    // ---- FC: 64 groups of 16 lanes; rows o = grp + 64k (k<2), 8 vols ----
    const int grp = tid >> 4;     // 0..63
    const int ll  = tid & 15;

    int oc[2];
    const v4f* wr[2];
    #pragma unroll
    for (int k = 0; k < 2; ++k) {
        const int o = grp + 64 * k;
        oc[k] = (o < NOUT) ? o : 0;
        wr[k] = fcw4 + oc[k] * 144;
    }

    float facc[2][8] = {};

    #pragma unroll 3
    for (int jj = 0; jj < 9; ++jj) {
        const int q  = ll + 16 * jj;
        const int cc = q / 9;                // channel of this quad

        const v4f  wq0 = wr[0][q];
        const v4f  wq1 = wr[1][q];
        const float a0 = attn_lds[oc[0] * 17 + cc];
        const float a1 = attn_lds[oc[1] * 17 + cc];
        const float s0x = a0 * wq0.x, s0y = a0 * wq0.y, s0z = a0 * wq0.z, s0w = a0 * wq0.w;
        const float s1x = a1 * wq1.x, s1y = a1 * wq1.y, s1z = a1 * wq1.z, s1w = a1 * wq1.w;

        #pragma unroll
        for (int vv = 0; vv < 8; ++vv) {
            const v4f xv = xms[2 * vv][q] + xms[2 * vv + 1][q];  // sum halves
            facc[0][vv] = fmaf(s0x, xv.x, facc[0][vv]);
            facc[0][vv] = fmaf(s0y, xv.y, facc[0][vv]);
            facc[0][vv] = fmaf(s0z, xv.z, facc[0][vv]);
            facc[0][vv] = fmaf(s0w, xv.w, facc[0][vv]);
            facc[1][vv] = fmaf(s1x, xv.x, facc[1][vv]);
            facc[1][vv] = fmaf(s1y, xv.y, facc[1][vv]);
            facc[1][vv] = fmaf(s1z, xv.z, facc[1][vv]);
            facc[1][vv] = fmaf(s1w, xv.w, facc[1][vv]);
        }
    }

    // transpose-reduce within 16 lanes: lanes 0-7 end with vols 0-7
    #pragma unroll
    for (int k = 0; k < 2; ++k) {
        float r4[4];
        #pragma unroll
        for (int j = 0; j < 4; ++j) {
            const float lo = facc[k][2 * j], hi = facc[k][2 * j + 1];
            const bool  up = (ll & 1);
            const float keep = up ? hi : lo;
            const float send = up ? lo : hi;
            r4[j] = keep + __shfl_xor(send, 1, 16);
        }
        float r2[2];
        #pragma unroll
        for (int j = 0; j < 2; ++j) {
            const float lo = r4[2 * j], hi = r4[2 * j + 1];
            const bool  up = (ll & 2);
            const float keep = up ? hi : lo;
            const float send = up ? lo : hi;
            r2[j] = keep + __shfl_xor(send, 2, 16);
        }
        float r1;
        {
            const float lo = r2[0], hi = r2[1];
            const bool  up = (ll & 4);
            const float keep = up ? hi : lo;
            const float send = up ? lo : hi;
            r1 = keep + __shfl_xor(send, 4, 16);
        }
        r1 += __shfl_xor(r1, 8, 16);         // lanes 0-7 hold vols 0-7

        const int o  = grp + 64 * k;
        const int bb = b0 + (ll & 7);
        if (ll < 8 && o < NOUT && bb < B)
            out[(size_t)bb * NOUT + o] = r1 + fcb[o];
    }
}

extern "C" void kernel_launch(void* const* d_in, const int* in_sizes, int n_in,
                              void* d_out, int out_size, void* d_ws, size_t ws_size,
                              hipStream_t stream) {
    const float* x   = (const float*)d_in[0];
    const float* dzh = (const float*)d_in[1];
    const float* dzl = (const float*)d_in[2];
    const float* fcw = (const float*)d_in[3];
    const float* fcb = (const float*)d_in[4];
    float* out = (float*)d_out;

    const int B = in_sizes[0] / (15 * 16 * 6 * 6);   // 4096
    const int blocks = (B + 7) / 8;                  // 512

    hipLaunchKernelGGL(bodyavg_hilo, dim3(blocks), dim3(1024), 0, stream,
                       reinterpret_cast<const v4f*>(x), dzh, dzl,
                       reinterpret_cast<const v4f*>(fcw), fcb, out, B);
}

// Round 12
// 33.417 us; speedup vs baseline: 1.1413x; 1.1413x over previous
//
#include <hip/hip_runtime.h>

#define NOUT 83
#define NHEART 27
#define NLUNG 28

typedef float v4f __attribute__((ext_vector_type(4)));

// one 16B global load, literal offset, NON-TEMPORAL (nt: bypass L1
// allocation -> test whether per-CU L1 miss tracking caps read BW).
// volatile asm -> compiler cannot split the chunk or shrink liveness.
#define GLOAD(dst, ptr, offs) \
    asm volatile("global_load_dwordx4 %0, %1, off offset:" offs " nt" \
                 : "=v"(dst) : "v"(ptr))

// Block: 512 threads = 8 waves; wave w owns volume b0+w, scans its 2160
// quads (33.75 KB) sequentially, 1 KB/step. 3 chunks of 9 steps + 6 + 1.
// Chunk: 9 asm loads (9 KB in flight) -> vmcnt(4) consume 5 -> vmcnt(0)
// consume 4. Position (64*i+l) mod 144, period 9 -> acc[i%9] static,
// merged via 9 LDS RMW into the wave-private xms region (lockstep-safe).
// FC: 32 groups x 16 lanes; group g -> rows o = g+32k (k<3) x 8 vols.
__global__ __launch_bounds__(512) void bodyavg_scan8nt(
    const v4f* __restrict__ x4,      // [B*2160] quads
    const float* __restrict__ dzh,   // [27,16]
    const float* __restrict__ dzl,   // [28,16]
    const v4f* __restrict__ fcw4,    // [83,144] quads
    const float* __restrict__ fcb,   // [83]
    float* __restrict__ out,         // [B,83]
    int B)
{
    __shared__ float attn_lds[NOUT * 17];
    __shared__ v4f   xms[8 * 144];           // per-volume slice-SUM

    const int tid = threadIdx.x;
    const int blk = blockIdx.x;
    const int b0  = blk * 8;

    const int w = tid >> 6;       // wave = volume slot 0..7
    const int l = tid & 63;
    const int b = b0 + w;

    // ---- Phase 1: sequential scan, one volume per wave, forced 9-deep ----
    v4f acc[9];
    #pragma unroll
    for (int j = 0; j < 9; ++j) acc[j] = (v4f){0.f, 0.f, 0.f, 0.f};

    if (b < B) {
        const v4f* src = x4 + (size_t)b * 2160 + l;
        const v4f* p0 = src;            // steps +0..+3   (offsets 0..3072)
        const v4f* p1 = src + 256;      // steps +4..+7
        const v4f* p2 = src + 512;      // step  +8

        #pragma unroll
        for (int c = 0; c < 3; ++c) {   // steps 0..26
            v4f t0, t1, t2, t3, t4, t5, t6, t7, t8;
            GLOAD(t0, p0, "0");    GLOAD(t1, p0, "1024");
            GLOAD(t2, p0, "2048"); GLOAD(t3, p0, "3072");
            GLOAD(t4, p1, "0");    GLOAD(t5, p1, "1024");
            GLOAD(t6, p1, "2048"); GLOAD(t7, p1, "3072");
            GLOAD(t8, p2, "0");
            asm volatile("s_waitcnt vmcnt(4)" ::: "memory");
            __builtin_amdgcn_sched_barrier(0);
            acc[0] += t0; acc[1] += t1; acc[2] += t2; acc[3] += t3; acc[4] += t4;
            asm volatile("s_waitcnt vmcnt(0)" ::: "memory");
            __builtin_amdgcn_sched_barrier(0);
            acc[5] += t5; acc[6] += t6; acc[7] += t7; acc[8] += t8;
            p0 += 576; p1 += 576; p2 += 576;
        }
        {   // tail steps 27..32 (j = 0..5)
            v4f t0, t1, t2, t3, t4, t5;
            GLOAD(t0, p0, "0");    GLOAD(t1, p0, "1024");
            GLOAD(t2, p0, "2048"); GLOAD(t3, p0, "3072");
            GLOAD(t4, p1, "0");    GLOAD(t5, p1, "1024");
            asm volatile("s_waitcnt vmcnt(0)" ::: "memory");
            __builtin_amdgcn_sched_barrier(0);
            acc[0] += t0; acc[1] += t1; acc[2] += t2;
            acc[3] += t3; acc[4] += t4; acc[5] += t5;
        }
        if (l < 48) acc[6] += src[2112];  // step 33 (partial, j = 6)
    }

    // zero own wave's region then merge (wave-private, lockstep-safe)
    {
        const v4f z = (v4f){0.f, 0.f, 0.f, 0.f};
        xms[w * 144 + l] = z;
        xms[w * 144 + 64 + l] = z;
        if (l < 16) xms[w * 144 + 128 + l] = z;
    }
    #pragma unroll
    for (int j = 0; j < 9; ++j) {
        int p = (64 * j) % 144 + l;      // < 192
        if (p >= 144) p -= 144;
        xms[w * 144 + p] += acc[j];
    }

    // ---- Phase 0: channel softmax (1/15 folded in), off critical path ----
    if (tid < NOUT) {
        const int o = tid;
        const float* row = (o < NHEART) ? (dzh + o * 16)
                                        : (dzl + ((o - NHEART) % NLUNG) * 16);
        float vals[16];
        #pragma unroll
        for (int c = 0; c < 16; ++c) vals[c] = row[c];
        float m = vals[0];
        #pragma unroll
        for (int c = 1; c < 16; ++c) m = fmaxf(m, vals[c]);
        float s = 0.f;
        #pragma unroll
        for (int c = 0; c < 16; ++c) { vals[c] = expf(vals[c] - m); s += vals[c]; }
        const float inv = (1.0f / s) * (1.0f / 15.0f);
        #pragma unroll
        for (int c = 0; c < 16; ++c) attn_lds[o * 17 + c] = vals[c] * inv;
    }

    __syncthreads();

    // ---- Phase 2: FC. 32 groups of 16 lanes; rows o = grp + 32k, k<3 ----
    const int grp = tid >> 4;     // 0..31
    const int ll  = tid & 15;

    int oc[3];
    const v4f* wr[3];
    #pragma unroll
    for (int k = 0; k < 3; ++k) {
        const int o = grp + 32 * k;
        oc[k] = (o < NOUT) ? o : 0;
        wr[k] = fcw4 + oc[k] * 144;
    }

    float facc[3][8] = {};

    #pragma unroll 3
    for (int jj = 0; jj < 9; ++jj) {
        const int q  = ll + 16 * jj;
        const int cc = q / 9;                // channel of this quad

        v4f xv[8];
        #pragma unroll
        for (int v = 0; v < 8; ++v) xv[v] = xms[v * 144 + q];

        #pragma unroll
        for (int k = 0; k < 3; ++k) {
            const v4f  wq = wr[k][q];
            const float a = attn_lds[oc[k] * 17 + cc];   // includes 1/15
            const float wx = a * wq.x, wy = a * wq.y, wz = a * wq.z, ww = a * wq.w;
            #pragma unroll
            for (int v = 0; v < 8; ++v) {
                facc[k][v] = fmaf(wx, xv[v].x, facc[k][v]);
                facc[k][v] = fmaf(wy, xv[v].y, facc[k][v]);
                facc[k][v] = fmaf(wz, xv[v].z, facc[k][v]);
                facc[k][v] = fmaf(ww, xv[v].w, facc[k][v]);
            }
        }
    }

    // transpose-reduce within 16 lanes: lanes 0-7 end with vols 0-7
    #pragma unroll
    for (int k = 0; k < 3; ++k) {
        float r4[4];
        #pragma unroll
        for (int j = 0; j < 4; ++j) {
            const float lo = facc[k][2 * j], hi = facc[k][2 * j + 1];
            const bool  up = (ll & 1);
            const float keep = up ? hi : lo;
            const float send = up ? lo : hi;
            r4[j] = keep + __shfl_xor(send, 1, 16);
        }
        float r2[2];
        #pragma unroll
        for (int j = 0; j < 2; ++j) {
            const float lo = r4[2 * j], hi = r4[2 * j + 1];
            const bool  up = (ll & 2);
            const float keep = up ? hi : lo;
            const float send = up ? lo : hi;
            r2[j] = keep + __shfl_xor(send, 2, 16);
        }
        float r1;
        {
            const float lo = r2[0], hi = r2[1];
            const bool  up = (ll & 4);
            const float keep = up ? hi : lo;
            const float send = up ? lo : hi;
            r1 = keep + __shfl_xor(send, 4, 16);
        }
        r1 += __shfl_xor(r1, 8, 16);         // lanes 0-7 hold vols 0-7

        const int o = grp + 32 * k;
        const int bb = b0 + (ll & 7);
        if (ll < 8 && o < NOUT && bb < B)
            out[(size_t)bb * NOUT + o] = r1 + fcb[o];
    }
}

extern "C" void kernel_launch(void* const* d_in, const int* in_sizes, int n_in,
                              void* d_out, int out_size, void* d_ws, size_t ws_size,
                              hipStream_t stream) {
    const float* x   = (const float*)d_in[0];
    const float* dzh = (const float*)d_in[1];
    const float* dzl = (const float*)d_in[2];
    const float* fcw = (const float*)d_in[3];
    const float* fcb = (const float*)d_in[4];
    float* out = (float*)d_out;

    const int B = in_sizes[0] / (15 * 16 * 6 * 6);   // 4096
    const int blocks = (B + 7) / 8;                  // 512

    hipLaunchKernelGGL(bodyavg_scan8nt, dim3(blocks), dim3(512), 0, stream,
                       reinterpret_cast<const v4f*>(x), dzh, dzl,
                       reinterpret_cast<const v4f*>(fcw), fcb, out, B);
}